// Round 6
// baseline (214.226 us; speedup 1.0000x reference)
//
#include <hip/hip_runtime.h>
#include <hip/hip_bf16.h>
#include <stdint.h>

// ---------------------------------------------------------------------------
// SelfAttention: QKV = X@W + b ; S = QK^T/32 (mask -> -inf) ; O = softmax(S)@V
// B=4, S=2048, H=1024.  bf16 MFMA path.
// R14: R13 + intra-tile read/MFMA pipelining. R13's COMP was serial per half:
//     {8 ds_read -> lgkmcnt(0) -> 16 MFMA} x2, exposing ~2x(read pipe+LDS
//     latency) per K-tile vs 310cy of MFMA -> MfmaUtil 26%. Now: issue all
//     16 reads up front, gate h0 MFMAs on lgkmcnt(8) (h1's reads stay in
//     flight under h0 compute), lgkmcnt(0) before h1 MFMAs. Separate reg
//     sets af0/bf0/af1/bf1. s_setprio(1) around MFMA clusters (2 desynced
//     blocks/CU = phase diversity, T5 regime). Same change in all 3 GEMMs.
// ---------------------------------------------------------------------------

typedef __attribute__((ext_vector_type(8))) short bf16x8;   // 8 bf16 = 4 VGPRs
typedef __attribute__((ext_vector_type(4))) float f32x4;

__device__ __forceinline__ void async_cp16(const void* g, void* l) {
  __builtin_amdgcn_global_load_lds(
      (const __attribute__((address_space(1))) void*)g,
      (__attribute__((address_space(3))) void*)l, 16, 0, 0);
}

__device__ __forceinline__ uint32_t laddr(const void* p) {
  return (uint32_t)(uintptr_t)(const __attribute__((address_space(3))) void*)p;
}

#define FENCE() asm volatile("" ::: "memory")
#define BAR()                           \
  do {                                  \
    FENCE();                            \
    __builtin_amdgcn_s_barrier();       \
    FENCE();                            \
  } while (0)
#define VMW(N) asm volatile("s_waitcnt vmcnt(" #N ")" ::: "memory")
#define LGKM(N)                                               \
  do {                                                        \
    asm volatile("s_waitcnt lgkmcnt(" #N ")" ::: "memory");   \
    __builtin_amdgcn_sched_barrier(0);                        \
  } while (0)
// asm ds_read_b128 with literal byte offset; no memory operand on purpose.
#define DSR(dst, a, OFF) \
  asm volatile("ds_read_b128 %0, %1 offset:" #OFF : "=v"(dst) : "v"(a))

// --------------------------- fp32 -> bf16 convert ---------------------------
__global__ void cvt_f32_bf16(const float* __restrict__ s,
                             __hip_bfloat16* __restrict__ d, int n) {
  int i = (blockIdx.x * blockDim.x + threadIdx.x) * 4;
  if (i >= n) return;
  float4 f = *(const float4*)(s + i);
  __hip_bfloat16 o[4];
  o[0] = __float2bfloat16(f.x);
  o[1] = __float2bfloat16(f.y);
  o[2] = __float2bfloat16(f.z);
  o[3] = __float2bfloat16(f.w);
  *(ushort4*)(d + i) = *(const ushort4*)o;
}

// -------------------- fp32 -> bf16 transposed (W -> W^T) --------------------
__global__ void transpose_cvt_f32(const float* __restrict__ src, int srcld,
                                  __hip_bfloat16* __restrict__ dst, int dstld) {
  __shared__ float tile[32][33];
  int bx = blockIdx.x * 32;   // src col
  int by = blockIdx.y * 32;   // src row
  int tx = threadIdx.x, ty = threadIdx.y;
#pragma unroll
  for (int j = 0; j < 4; ++j)
    tile[ty + j * 8][tx] = src[(int64_t)(by + ty + j * 8) * srcld + bx + tx];
  __syncthreads();
#pragma unroll
  for (int j = 0; j < 4; ++j)
    dst[(int64_t)(bx + ty + j * 8) * dstld + by + tx] =
        __float2bfloat16(tile[tx][ty + j * 8]);
}

// ------------------------------ mask scan ----------------------------------
__global__ __launch_bounds__(256) void mask_scan(const int* __restrict__ mask,
                                                 int* __restrict__ idx,
                                                 int* __restrict__ cnt,
                                                 int* __restrict__ cnt_pad) {
  const int b = blockIdx.x;
  mask += b * 2048;
  idx += b * 2048;
  const int t = threadIdx.x;
  const int lane = t & 63, wave = t >> 6;

  int keep[8];
  int local = 0;
#pragma unroll
  for (int j = 0; j < 8; ++j) {
    keep[j] = (mask[t * 8 + j] == 0);
    local += keep[j];
  }
  int pre = local;  // inclusive wave scan
#pragma unroll
  for (int off = 1; off <= 32; off <<= 1) {
    int n = __shfl_up(pre, off, 64);
    if (lane >= off) pre += n;
  }
  __shared__ int wsum[4];
  if (lane == 63) wsum[wave] = pre;
  __syncthreads();
  int base = 0;
  for (int w = 0; w < wave; ++w) base += wsum[w];
  int excl = base + pre - local;
#pragma unroll
  for (int j = 0; j < 8; ++j)
    if (keep[j]) idx[excl++] = t * 8 + j;
  if (t == 255) {
    int tot = base + pre;
    cnt[b] = tot;
    cnt_pad[b] = (tot + 127) & ~127;
  }
}

// --------------------------- merged Q+K+V GEMM -----------------------------
// grid (384, 1, B).  Swizzled flat id: xcd=f&7, loc=f>>3 in [0,48):
//   m_idx = (loc&7)*2 + (xcd>>2); n_idx = (loc>>3)*4 + (xcd&3) in [0,24)
// n_idx<8:  Q  = Xb[z] @ Wt[0:1024]^T + b      (all 2048 rows)
// n_idx>=8: KV = gather(Xb[z], idx) @ Wt[1024:3072]^T + b, rows < cnt_pad[z]
// 128x128 tile, 256 thr, BK=64, dbuf prefetch, pipelined asm ds_read COMP.
__global__ __launch_bounds__(256) void gemm_qkv(
    const __hip_bfloat16* __restrict__ Xb, const __hip_bfloat16* __restrict__ Wt,
    const float* __restrict__ bias, const int* __restrict__ idx,
    const int* __restrict__ cnt, const int* __restrict__ cnt_pad,
    __hip_bfloat16* __restrict__ Q, __hip_bfloat16* __restrict__ Kc,
    __hip_bfloat16* __restrict__ Vt) {
  const int z = blockIdx.z;
  const int f = blockIdx.x;
  const int xcd = f & 7, loc = f >> 3;
  const int m0 = ((loc & 7) * 2 + (xcd >> 2)) * 128;
  const int n_idx = (loc >> 3) * 4 + (xcd & 3);
  const bool isQ = (n_idx < 8);
  if (!isQ && m0 >= cnt_pad[z]) return;
  const int n0 = (isQ ? n_idx : n_idx - 8) * 128;
  const __hip_bfloat16* A = Xb + (int64_t)z * 2048 * 1024;
  const __hip_bfloat16* Bt = Wt + (isQ ? 0 : (int64_t)1024 * 1024);
  const float* bv = bias + (isQ ? 0 : 1024);

  const int tid = threadIdx.x;
  const int wave = tid >> 6, lane = tid & 63;
  const int quad = lane >> 4, tr = lane & 15, t7 = tr & 7;
  const int wm = wave & 1, wn = wave >> 1;

  // 2 bufs x (lsA 8192 el + lsB 8192 el) = 64KB; V-epilogue reuses as
  // vt[128][136].
  __shared__ __hip_bfloat16 ls[32768];

  // 32 chunks of 1KB (8 rows x 128B each): 0..15 = A, 16..31 = B. 8/wave.
  const __hip_bfloat16* gsrc[8];
  int loff[8];  // element offset within one buffer
  {
    const int srow = lane >> 3;                 // 0..7
    const int kcs = (((lane & 7) ^ srow) * 8);  // swizzled k-chunk (elements)
    const int cz = isQ ? 0 : cnt[z];
    const int* idxz = idx + z * 2048;
#pragma unroll
    for (int cc = 0; cc < 8; ++cc) {
      int c = wave * 8 + cc;
      int isA = (c < 16);
      int cr = isA ? c : (c - 16);
      int row = cr * 8 + srow;
      if (isA) {
        int ar = m0 + row;
        if (!isQ) ar = (ar < cz) ? idxz[ar] : 0;
        gsrc[cc] = A + (int64_t)ar * 1024 + kcs;
      } else {
        gsrc[cc] = Bt + (int64_t)(n0 + row) * 1024 + kcs;
      }
      loff[cc] = (isA ? 0 : 8192) + cr * 512;
    }
  }

  // LDS byte addrs for asm fragment reads (buf, k-half w).
  uint32_t aAd[2][2], bBd[2][2];
  {
    uint32_t base = laddr(ls);
#pragma unroll
    for (int b = 0; b < 2; ++b)
#pragma unroll
      for (int w = 0; w < 2; ++w) {
        uint32_t col = (uint32_t)(((((w << 2) | quad)) ^ t7) * 16);
        aAd[b][w] = base + b * 32768 + (wm * 64 + tr) * 128 + col;
        bBd[b][w] = base + b * 32768 + 16384 + (wn * 64 + tr) * 128 + col;
      }
  }

  f32x4 acc[4][4];
#pragma unroll
  for (int mi = 0; mi < 4; ++mi)
#pragma unroll
    for (int ni = 0; ni < 4; ++ni) acc[mi][ni] = (f32x4){0.f, 0.f, 0.f, 0.f};

  bf16x8 af0[4], bf0[4], af1[4], bf1[4];

#define STAGE(BUF, k0)                                            \
  do {                                                            \
    _Pragma("unroll") for (int cc = 0; cc < 8; ++cc)              \
        async_cp16(gsrc[cc] + (k0), ls + (BUF)*16384 + loff[cc]); \
  } while (0)
#define COMP(BUF)                                                             \
  do {                                                                        \
    DSR(af0[0], aAd[BUF][0], 0);                                              \
    DSR(af0[1], aAd[BUF][0], 2048);                                           \
    DSR(af0[2], aAd[BUF][0], 4096);                                           \
    DSR(af0[3], aAd[BUF][0], 6144);                                           \
    DSR(bf0[0], bBd[BUF][0], 0);                                              \
    DSR(bf0[1], bBd[BUF][0], 2048);                                           \
    DSR(bf0[2], bBd[BUF][0], 4096);                                           \
    DSR(bf0[3], bBd[BUF][0], 6144);                                           \
    DSR(af1[0], aAd[BUF][1], 0);                                              \
    DSR(af1[1], aAd[BUF][1], 2048);                                           \
    DSR(af1[2], aAd[BUF][1], 4096);                                           \
    DSR(af1[3], aAd[BUF][1], 6144);                                           \
    DSR(bf1[0], bBd[BUF][1], 0);                                              \
    DSR(bf1[1], bBd[BUF][1], 2048);                                           \
    DSR(bf1[2], bBd[BUF][1], 4096);                                           \
    DSR(bf1[3], bBd[BUF][1], 6144);                                           \
    LGKM(8); /* h0's 8 done; h1's 8 in flight under h0 MFMAs */               \
    __builtin_amdgcn_s_setprio(1);                                            \
    _Pragma("unroll") for (int mi = 0; mi < 4; ++mi)                          \
        _Pragma("unroll") for (int ni = 0; ni < 4; ++ni) acc[mi][ni] =        \
            __builtin_amdgcn_mfma_f32_16x16x32_bf16(af0[mi], bf0[ni],         \
                                                    acc[mi][ni], 0, 0, 0);    \
    __builtin_amdgcn_s_setprio(0);                                            \
    LGKM(0);                                                                  \
    __builtin_amdgcn_s_setprio(1);                                            \
    _Pragma("unroll") for (int mi = 0; mi < 4; ++mi)                          \
        _Pragma("unroll") for (int ni = 0; ni < 4; ++ni) acc[mi][ni] =        \
            __builtin_amdgcn_mfma_f32_16x16x32_bf16(af1[mi], bf1[ni],         \
                                                    acc[mi][ni], 0, 0, 0);    \
    __builtin_amdgcn_s_setprio(0);                                            \
  } while (0)

  STAGE(0, 0);
  for (int it = 0; it < 8; ++it) {
    STAGE(1, (2 * it + 1) * 64);
    VMW(8); BAR();
    COMP(0);
    BAR();
    if (it < 7) {
      STAGE(0, (2 * it + 2) * 64);
      VMW(8);
    } else {
      VMW(0);
    }
    BAR();
    COMP(1);
    BAR();
  }
#undef STAGE
#undef COMP

  // Epilogue. D element (row,col) in 16x16 tile = (quad*4 + r, tr)  [m89]
  const int rowbase = m0 + wm * 64;
  const int colbase = n0 + wn * 64;
  if (isQ) {
    __hip_bfloat16* C = Q + (int64_t)z * 2048 * 1024;
#pragma unroll
    for (int ni = 0; ni < 4; ++ni) {
      int col = colbase + ni * 16 + tr;
      float bb = bv[col];
#pragma unroll
      for (int mi = 0; mi < 4; ++mi) {
        int row = rowbase + mi * 16 + quad * 4;
#pragma unroll
        for (int r = 0; r < 4; ++r)
          C[(int64_t)(row + r) * 1024 + col] =
              __float2bfloat16(acc[mi][ni][r] + bb);
      }
    }
  } else if (n0 < 1024) {  // K half
    __hip_bfloat16* C = Kc + (int64_t)z * 2048 * 1024;
#pragma unroll
    for (int ni = 0; ni < 4; ++ni) {
      int col = colbase + ni * 16 + tr;
      float bb = bv[col];
#pragma unroll
      for (int mi = 0; mi < 4; ++mi) {
        int row = rowbase + mi * 16 + quad * 4;
#pragma unroll
        for (int r = 0; r < 4; ++r)
          C[(int64_t)(row + r) * 1024 + col] =
              __float2bfloat16(acc[mi][ni][r] + bb);
      }
    }
  } else {  // V half -> LDS transpose -> coalesced Vt rows
    __syncthreads();
#pragma unroll
    for (int ni = 0; ni < 4; ++ni) {
      int cl = wn * 64 + ni * 16 + tr;  // block-local d
      float bb = bv[colbase + ni * 16 + tr];
#pragma unroll
      for (int mi = 0; mi < 4; ++mi) {
        int rl = wm * 64 + mi * 16 + quad * 4;  // block-local key
        __hip_bfloat16 h[4];
#pragma unroll
        for (int r = 0; r < 4; ++r) h[r] = __float2bfloat16(acc[mi][ni][r] + bb);
        *(ushort4*)(ls + cl * 136 + rl) = *(const ushort4*)h;
      }
    }
    __syncthreads();
    __hip_bfloat16* Vz = Vt + (int64_t)z * 1024 * 2048;
    const int d0 = n0 - 1024;
    const int seg = tid & 15;
#pragma unroll
    for (int p = 0; p < 8; ++p) {
      int d = p * 16 + (tid >> 4);
      bf16x8 v = *(const bf16x8*)(ls + d * 136 + seg * 8);
      *(bf16x8*)(Vz + (int64_t)(d0 + d) * 2048 + m0 + seg * 8) = v;
    }
  }
}

// ------------------------ scores GEMM + fused exp --------------------------
// e = exp2(scale2 * (Q@Kc^T)) bf16; cols >= cnt -> 0. Row sums -> atomicAdd.
// 128x128 tile, BK=64, dbuf prefetch, pipelined asm ds_read COMP.
__global__ __launch_bounds__(256) void gemm_scores(
    const __hip_bfloat16* __restrict__ Qb, const __hip_bfloat16* __restrict__ Kc,
    __hip_bfloat16* __restrict__ Sc, float* __restrict__ rowsum,
    const int* __restrict__ cnt, const int* __restrict__ cnt_pad,
    float scale2) {
  const int z = blockIdx.z;
  const int f = blockIdx.x;
  const int xcd = f & 7, loc = f >> 3;
  const int m0 = ((loc & 7) * 2 + (xcd >> 2)) * 128;
  const int n0 = ((loc >> 3) * 4 + (xcd & 3)) * 128;
  if (n0 >= cnt_pad[z]) return;
  const __hip_bfloat16* A = Qb + (int64_t)z * 2048 * 1024;
  const __hip_bfloat16* Bt = Kc + (int64_t)z * 2048 * 1024;

  const int tid = threadIdx.x;
  const int wave = tid >> 6, lane = tid & 63;
  const int quad = lane >> 4, tr = lane & 15, t7 = tr & 7;
  const int wm = wave & 1, wn = wave >> 1;

  __shared__ __hip_bfloat16 ls[32768];

  const __hip_bfloat16* gsrc[8];
  int loff[8];
  {
    const int srow = lane >> 3;
    const int kcs = (((lane & 7) ^ srow) * 8);
#pragma unroll
    for (int cc = 0; cc < 8; ++cc) {
      int c = wave * 8 + cc;
      int isA = (c < 16);
      int cr = isA ? c : (c - 16);
      int row = cr * 8 + srow;
      gsrc[cc] = isA ? (A + (int64_t)(m0 + row) * 1024 + kcs)
                     : (Bt + (int64_t)(n0 + row) * 1024 + kcs);
      loff[cc] = (isA ? 0 : 8192) + cr * 512;
    }
  }

  uint32_t aAd[2][2], bBd[2][2];
  {
    uint32_t base = laddr(ls);
#pragma unroll
    for (int b = 0; b < 2; ++b)
#pragma unroll
      for (int w = 0; w < 2; ++w) {
        uint32_t col = (uint32_t)(((((w << 2) | quad)) ^ t7) * 16);
        aAd[b][w] = base + b * 32768 + (wm * 64 + tr) * 128 + col;
        bBd[b][w] = base + b * 32768 + 16384 + (wn * 64 + tr) * 128 + col;
      }
  }

  f32x4 acc[4][4];
#pragma unroll
  for (int mi = 0; mi < 4; ++mi)
#pragma unroll
    for (int ni = 0; ni < 4; ++ni) acc[mi][ni] = (f32x4){0.f, 0.f, 0.f, 0.f};

  bf16x8 af0[4], bf0[4], af1[4], bf1[4];

#define STAGE(BUF, k0)                                            \
  do {                                                            \
    _Pragma("unroll") for (int cc = 0; cc < 8; ++cc)              \
        async_cp16(gsrc[cc] + (k0), ls + (BUF)*16384 + loff[cc]); \
  } while (0)
#define COMP(BUF)                                                             \
  do {                                                                        \
    DSR(af0[0], aAd[BUF][0], 0);                                              \
    DSR(af0[1], aAd[BUF][0], 2048);                                           \
    DSR(af0[2], aAd[BUF][0], 4096);                                           \
    DSR(af0[3], aAd[BUF][0], 6144);                                           \
    DSR(bf0[0], bBd[BUF][0], 0);                                              \
    DSR(bf0[1], bBd[BUF][0], 2048);                                           \
    DSR(bf0[2], bBd[BUF][0], 4096);                                           \
    DSR(bf0[3], bBd[BUF][0], 6144);                                           \
    DSR(af1[0], aAd[BUF][1], 0);                                              \
    DSR(af1[1], aAd[BUF][1], 2048);                                           \
    DSR(af1[2], aAd[BUF][1], 4096);                                           \
    DSR(af1[3], aAd[BUF][1], 6144);                                           \
    DSR(bf1[0], bBd[BUF][1], 0);                                              \
    DSR(bf1[1], bBd[BUF][1], 2048);                                           \
    DSR(bf1[2], bBd[BUF][1], 4096);                                           \
    DSR(bf1[3], bBd[BUF][1], 6144);                                           \
    LGKM(8);                                                                  \
    __builtin_amdgcn_s_setprio(1);                                            \
    _Pragma("unroll") for (int mi = 0; mi < 4; ++mi)                          \
        _Pragma("unroll") for (int ni = 0; ni < 4; ++ni) acc[mi][ni] =        \
            __builtin_amdgcn_mfma_f32_16x16x32_bf16(af0[mi], bf0[ni],         \
                                                    acc[mi][ni], 0, 0, 0);    \
    __builtin_amdgcn_s_setprio(0);                                            \
    LGKM(0);                                                                  \
    __builtin_amdgcn_s_setprio(1);                                            \
    _Pragma("unroll") for (int mi = 0; mi < 4; ++mi)                          \
        _Pragma("unroll") for (int ni = 0; ni < 4; ++ni) acc[mi][ni] =        \
            __builtin_amdgcn_mfma_f32_16x16x32_bf16(af1[mi], bf1[ni],         \
                                                    acc[mi][ni], 0, 0, 0);    \
    __builtin_amdgcn_s_setprio(0);                                            \
  } while (0)

  STAGE(0, 0);
  for (int it = 0; it < 8; ++it) {
    STAGE(1, (2 * it + 1) * 64);
    VMW(8); BAR();
    COMP(0);
    BAR();
    if (it < 7) {
      STAGE(0, (2 * it + 2) * 64);
      VMW(8);
    } else {
      VMW(0);
    }
    BAR();
    COMP(1);
    BAR();
  }
#undef STAGE
#undef COMP

  const int rowbase = m0 + wm * 64;
  const int colbase = n0 + wn * 64;
  const int cn = cnt[z];
  __hip_bfloat16* C = Sc + (int64_t)z * 2048 * 2048;

  float psum[4][4];
#pragma unroll
  for (int mi = 0; mi < 4; ++mi)
#pragma unroll
    for (int r = 0; r < 4; ++r) psum[mi][r] = 0.f;

#pragma unroll
  for (int ni = 0; ni < 4; ++ni) {
    int col = colbase + ni * 16 + tr;
    bool valid = (col < cn);
#pragma unroll
    for (int mi = 0; mi < 4; ++mi) {
      int row = rowbase + mi * 16 + quad * 4;
#pragma unroll
      for (int r = 0; r < 4; ++r) {
        float e = valid ? exp2f(acc[mi][ni][r] * scale2) : 0.f;
        C[(int64_t)(row + r) * 2048 + col] = __float2bfloat16(e);
        psum[mi][r] += e;
      }
    }
  }
#pragma unroll
  for (int off = 1; off <= 8; off <<= 1)
#pragma unroll
    for (int mi = 0; mi < 4; ++mi)
#pragma unroll
      for (int r = 0; r < 4; ++r)
        psum[mi][r] += __shfl_xor(psum[mi][r], off, 64);
  if (tr == 0) {
    float* rs = rowsum + z * 2048 + rowbase;
#pragma unroll
    for (int mi = 0; mi < 4; ++mi)
#pragma unroll
      for (int r = 0; r < 4; ++r)
        atomicAdd(&rs[mi * 16 + quad * 4 + r], psum[mi][r]);
  }
}

// --------------------------- PV GEMM + normalize ---------------------------
// out = (E @ Vt^T) / rowsum[row]  (fp32). K = cnt_pad[z]. 128x128 tile,
// BK=64, dbuf prefetch, pipelined asm ds_read COMP. grid (128,1,4).
__global__ __launch_bounds__(256) void gemm_pv(
    const __hip_bfloat16* __restrict__ Sc, const __hip_bfloat16* __restrict__ Vt,
    float* __restrict__ out, const float* __restrict__ rowsum,
    const int* __restrict__ cnt_pad) {
  const int z = blockIdx.z;
  const int f = blockIdx.x;
  const int xcd = f & 7, loc = f >> 3;
  const int m0 = ((loc & 7) * 2 + (xcd >> 2)) * 128;
  const int n0 = ((loc >> 3) * 4 + (xcd & 3)) * 128;
  const int Ks = cnt_pad[z];
  const __hip_bfloat16* A = Sc + (int64_t)z * 2048 * 2048;
  const __hip_bfloat16* Bt = Vt + (int64_t)z * 1024 * 2048;

  const int tid = threadIdx.x;
  const int wave = tid >> 6, lane = tid & 63;
  const int quad = lane >> 4, tr = lane & 15, t7 = tr & 7;
  const int wm = wave & 1, wn = wave >> 1;

  __shared__ __hip_bfloat16 ls[32768];

  const __hip_bfloat16* gsrc[8];
  int loff[8];
  {
    const int srow = lane >> 3;
    const int kcs = (((lane & 7) ^ srow) * 8);
#pragma unroll
    for (int cc = 0; cc < 8; ++cc) {
      int c = wave * 8 + cc;
      int isA = (c < 16);
      int cr = isA ? c : (c - 16);
      int row = cr * 8 + srow;
      gsrc[cc] = isA ? (A + (int64_t)(m0 + row) * 2048 + kcs)
                     : (Bt + (int64_t)(n0 + row) * 2048 + kcs);
      loff[cc] = (isA ? 0 : 8192) + cr * 512;
    }
  }

  uint32_t aAd[2][2], bBd[2][2];
  {
    uint32_t base = laddr(ls);
#pragma unroll
    for (int b = 0; b < 2; ++b)
#pragma unroll
      for (int w = 0; w < 2; ++w) {
        uint32_t col = (uint32_t)(((((w << 2) | quad)) ^ t7) * 16);
        aAd[b][w] = base + b * 32768 + (wm * 64 + tr) * 128 + col;
        bBd[b][w] = base + b * 32768 + 16384 + (wn * 64 + tr) * 128 + col;
      }
  }

  f32x4 acc[4][4];
#pragma unroll
  for (int mi = 0; mi < 4; ++mi)
#pragma unroll
    for (int ni = 0; ni < 4; ++ni) acc[mi][ni] = (f32x4){0.f, 0.f, 0.f, 0.f};

  bf16x8 af0[4], bf0[4], af1[4], bf1[4];

#define STAGE(BUF, k0)                                            \
  do {                                                            \
    _Pragma("unroll") for (int cc = 0; cc < 8; ++cc)              \
        async_cp16(gsrc[cc] + (k0), ls + (BUF)*16384 + loff[cc]); \
  } while (0)
#define COMP(BUF)                                                             \
  do {                                                                        \
    DSR(af0[0], aAd[BUF][0], 0);                                              \
    DSR(af0[1], aAd[BUF][0], 2048);                                           \
    DSR(af0[2], aAd[BUF][0], 4096);                                           \
    DSR(af0[3], aAd[BUF][0], 6144);                                           \
    DSR(bf0[0], bBd[BUF][0], 0);                                              \
    DSR(bf0[1], bBd[BUF][0], 2048);                                           \
    DSR(bf0[2], bBd[BUF][0], 4096);                                           \
    DSR(bf0[3], bBd[BUF][0], 6144);                                           \
    DSR(af1[0], aAd[BUF][1], 0);                                              \
    DSR(af1[1], aAd[BUF][1], 2048);                                           \
    DSR(af1[2], aAd[BUF][1], 4096);                                           \
    DSR(af1[3], aAd[BUF][1], 6144);                                           \
    DSR(bf1[0], bBd[BUF][1], 0);                                              \
    DSR(bf1[1], bBd[BUF][1], 2048);                                           \
    DSR(bf1[2], bBd[BUF][1], 4096);                                           \
    DSR(bf1[3], bBd[BUF][1], 6144);                                           \
    LGKM(8);                                                                  \
    __builtin_amdgcn_s_setprio(1);                                            \
    _Pragma("unroll") for (int mi = 0; mi < 4; ++mi)                          \
        _Pragma("unroll") for (int ni = 0; ni < 4; ++ni) acc[mi][ni] =        \
            __builtin_amdgcn_mfma_f32_16x16x32_bf16(af0[mi], bf0[ni],         \
                                                    acc[mi][ni], 0, 0, 0);    \
    __builtin_amdgcn_s_setprio(0);                                            \
    LGKM(0);                                                                  \
    __builtin_amdgcn_s_setprio(1);                                            \
    _Pragma("unroll") for (int mi = 0; mi < 4; ++mi)                          \
        _Pragma("unroll") for (int ni = 0; ni < 4; ++ni) acc[mi][ni] =        \
            __builtin_amdgcn_mfma_f32_16x16x32_bf16(af1[mi], bf1[ni],         \
                                                    acc[mi][ni], 0, 0, 0);    \
    __builtin_amdgcn_s_setprio(0);                                            \
  } while (0)

  const int NP = Ks >> 7;  // K-tile pairs (cnt_pad is 128-aligned)
  STAGE(0, 0);
  for (int it = 0; it < NP; ++it) {
    STAGE(1, (2 * it + 1) * 64);
    VMW(8); BAR();
    COMP(0);
    BAR();
    if (it + 1 < NP) {
      STAGE(0, (2 * it + 2) * 64);
      VMW(8);
    } else {
      VMW(0);
    }
    BAR();
    COMP(1);
    BAR();
  }
#undef STAGE
#undef COMP

  const int rowbase = m0 + wm * 64;
  const int colbase = n0 + wn * 64;
  const float* rs = rowsum + z * 2048 + rowbase;
  float invv[4][4];
#pragma unroll
  for (int mi = 0; mi < 4; ++mi)
#pragma unroll
    for (int r = 0; r < 4; ++r) invv[mi][r] = 1.0f / rs[mi * 16 + quad * 4 + r];

  float* C = out + (int64_t)z * 2048 * 1024;
#pragma unroll
  for (int ni = 0; ni < 4; ++ni) {
    int col = colbase + ni * 16 + tr;
#pragma unroll
    for (int mi = 0; mi < 4; ++mi) {
      int row = rowbase + mi * 16 + quad * 4;
#pragma unroll
      for (int r = 0; r < 4; ++r)
        C[(int64_t)(row + r) * 1024 + col] = acc[mi][ni][r] * invv[mi][r];
    }
  }
}

// ------------------------------- launcher ----------------------------------
extern "C" void kernel_launch(void* const* d_in, const int* in_sizes, int n_in,
                              void* d_out, int out_size, void* d_ws,
                              size_t ws_size, hipStream_t stream) {
  const float* X = (const float*)d_in[0];        // (4,2048,1024) fp32
  const int* mask = (const int*)d_in[1];         // (4,2048) bool->int32
  const float* W = (const float*)d_in[2];        // (1024,3072) fp32
  const float* bias = (const float*)d_in[3];     // (3072,) fp32
  float* out = (float*)d_out;                    // (4,2048,1024) fp32

  char* ws = (char*)d_ws;
  auto alloc = [&](size_t bytes) {
    char* p = ws;
    ws += (bytes + 255) & ~(size_t)255;
    return p;
  };
  __hip_bfloat16* Xb = (__hip_bfloat16*)alloc(8192ULL * 1024 * 2);      // 16.8 MB
  __hip_bfloat16* Wt = (__hip_bfloat16*)alloc(3072ULL * 1024 * 2);      //  6.3 MB
  __hip_bfloat16* Q = (__hip_bfloat16*)alloc(8192ULL * 1024 * 2);       // 16.8 MB
  __hip_bfloat16* Kc = (__hip_bfloat16*)alloc(4ULL * 2048 * 1024 * 2);  // 16.8 MB
  __hip_bfloat16* Vt = (__hip_bfloat16*)alloc(4ULL * 1024 * 2048 * 2);  // 16.8 MB
  __hip_bfloat16* Sc = (__hip_bfloat16*)alloc(4ULL * 2048 * 2048 * 2);  // 33.6 MB
  float* rowsum = (float*)alloc(8192ULL * 4);                           // 32 KB
  int* idx = (int*)alloc(4ULL * 2048 * 4);
  int* cnt = (int*)alloc(64);
  int* cnt_pad = (int*)alloc(64);

  // 0) rowsum = 0 (ws is poisoned 0xAA before every launch)
  hipMemsetAsync(rowsum, 0, 8192ULL * 4, stream);
  // 1) X -> bf16
  cvt_f32_bf16<<<8192, 256, 0, stream>>>(X, Xb, 8192 * 1024);
  // 2) W -> W^T bf16  (Bt layout [N][K])
  transpose_cvt_f32<<<dim3(96, 32, 1), dim3(32, 8), 0, stream>>>(W, 3072, Wt,
                                                                 1024);
  // 3) mask -> compacted index list (cnt_pad 128-aligned)
  mask_scan<<<4, 256, 0, stream>>>(mask, idx, cnt, cnt_pad);
  // 4) merged Q + K + V^T (swizzled; V transposed via LDS in epilogue)
  gemm_qkv<<<dim3(384, 1, 4), 256, 0, stream>>>(Xb, Wt, bias, idx, cnt,
                                                cnt_pad, Q, Kc, Vt);
  // 5) E = exp2(log2e/32 * Q@Kc^T) -> bf16, rowsum += per-row sums
  gemm_scores<<<dim3(256, 1, 4), 256, 0, stream>>>(
      Q, Kc, Sc, rowsum, cnt, cnt_pad, 0.03125f * 1.4426950408889634f);
  // 6) out = (E @ Vt^T) / rowsum  (fp32, K = cnt_pad)
  gemm_pv<<<dim3(128, 1, 4), 256, 0, stream>>>(Sc, Vt, out, rowsum, cnt_pad);
}

// Round 7
// 208.489 us; speedup vs baseline: 1.0275x; 1.0275x over previous
//
#include <hip/hip_runtime.h>
#include <hip/hip_bf16.h>
#include <stdint.h>

// ---------------------------------------------------------------------------
// SelfAttention: QKV = X@W + b ; S = QK^T/32 (mask -> -inf) ; O = softmax(S)@V
// B=4, S=2048, H=1024.  bf16 MFMA path.
// R15: m97-structure k-loop (single-buffer LDS, 2 barriers/tile, drain
//     vmcnt(0) per tile) + 4 blocks/CU (__launch_bounds__(256,4), LDS
//     <=35KB) + R13's asm-read COMP. R14 falsified intra-tile read
//     serialization as the stall; R13 (dbuf, 2 blk/CU) = 670 TF. The
//     HW-proven 874-912 TF recipe (m97/m103/m114) hides each block's
//     per-tile DMA drain with 3 OTHER resident blocks' compute instead of
//     explicit prefetch -- the one structure cell not yet tried with
//     asm-read COMP (R8 had compiler-COMP = implicit re-drains).
// ---------------------------------------------------------------------------

typedef __attribute__((ext_vector_type(8))) short bf16x8;   // 8 bf16 = 4 VGPRs
typedef __attribute__((ext_vector_type(4))) float f32x4;

__device__ __forceinline__ void async_cp16(const void* g, void* l) {
  __builtin_amdgcn_global_load_lds(
      (const __attribute__((address_space(1))) void*)g,
      (__attribute__((address_space(3))) void*)l, 16, 0, 0);
}

__device__ __forceinline__ uint32_t laddr(const void* p) {
  return (uint32_t)(uintptr_t)(const __attribute__((address_space(3))) void*)p;
}

#define FENCE() asm volatile("" ::: "memory")
#define BAR()                           \
  do {                                  \
    FENCE();                            \
    __builtin_amdgcn_s_barrier();       \
    FENCE();                            \
  } while (0)
#define VMW(N) asm volatile("s_waitcnt vmcnt(" #N ")" ::: "memory")
#define LGKM0()                                               \
  do {                                                        \
    asm volatile("s_waitcnt lgkmcnt(0)" ::: "memory");        \
    __builtin_amdgcn_sched_barrier(0);                        \
  } while (0)
// asm ds_read_b128 with literal byte offset; no memory operand on purpose.
#define DSR(dst, a, OFF) \
  asm volatile("ds_read_b128 %0, %1 offset:" #OFF : "=v"(dst) : "v"(a))

// --------------------------- fp32 -> bf16 convert ---------------------------
__global__ void cvt_f32_bf16(const float* __restrict__ s,
                             __hip_bfloat16* __restrict__ d, int n) {
  int i = (blockIdx.x * blockDim.x + threadIdx.x) * 4;
  if (i >= n) return;
  float4 f = *(const float4*)(s + i);
  __hip_bfloat16 o[4];
  o[0] = __float2bfloat16(f.x);
  o[1] = __float2bfloat16(f.y);
  o[2] = __float2bfloat16(f.z);
  o[3] = __float2bfloat16(f.w);
  *(ushort4*)(d + i) = *(const ushort4*)o;
}

// -------------------- fp32 -> bf16 transposed (W -> W^T) --------------------
__global__ void transpose_cvt_f32(const float* __restrict__ src, int srcld,
                                  __hip_bfloat16* __restrict__ dst, int dstld) {
  __shared__ float tile[32][33];
  int bx = blockIdx.x * 32;   // src col
  int by = blockIdx.y * 32;   // src row
  int tx = threadIdx.x, ty = threadIdx.y;
#pragma unroll
  for (int j = 0; j < 4; ++j)
    tile[ty + j * 8][tx] = src[(int64_t)(by + ty + j * 8) * srcld + bx + tx];
  __syncthreads();
#pragma unroll
  for (int j = 0; j < 4; ++j)
    dst[(int64_t)(bx + ty + j * 8) * dstld + by + tx] =
        __float2bfloat16(tile[tx][ty + j * 8]);
}

// ------------------------------ mask scan ----------------------------------
__global__ __launch_bounds__(256) void mask_scan(const int* __restrict__ mask,
                                                 int* __restrict__ idx,
                                                 int* __restrict__ cnt,
                                                 int* __restrict__ cnt_pad) {
  const int b = blockIdx.x;
  mask += b * 2048;
  idx += b * 2048;
  const int t = threadIdx.x;
  const int lane = t & 63, wave = t >> 6;

  int keep[8];
  int local = 0;
#pragma unroll
  for (int j = 0; j < 8; ++j) {
    keep[j] = (mask[t * 8 + j] == 0);
    local += keep[j];
  }
  int pre = local;  // inclusive wave scan
#pragma unroll
  for (int off = 1; off <= 32; off <<= 1) {
    int n = __shfl_up(pre, off, 64);
    if (lane >= off) pre += n;
  }
  __shared__ int wsum[4];
  if (lane == 63) wsum[wave] = pre;
  __syncthreads();
  int base = 0;
  for (int w = 0; w < wave; ++w) base += wsum[w];
  int excl = base + pre - local;
#pragma unroll
  for (int j = 0; j < 8; ++j)
    if (keep[j]) idx[excl++] = t * 8 + j;
  if (t == 255) {
    int tot = base + pre;
    cnt[b] = tot;
    cnt_pad[b] = (tot + 127) & ~127;
  }
}

// --------------------------- merged Q+K+V GEMM -----------------------------
// grid (384, 1, B).  Swizzled flat id: xcd=f&7, loc=f>>3 in [0,48):
//   m_idx = (loc&7)*2 + (xcd>>2); n_idx = (loc>>3)*4 + (xcd&3) in [0,24)
// n_idx<8:  Q  = Xb[z] @ Wt[0:1024]^T + b      (all 2048 rows)
// n_idx>=8: KV = gather(Xb[z], idx) @ Wt[1024:3072]^T + b, rows < cnt_pad[z]
// 128x128 tile, 256 thr, BK=64, SINGLE-buffer m97 loop, asm ds_read COMP.
// LDS 34.8KB (17408 el; staging uses 16384, V-epilogue uses all) -> 4 blk/CU.
__global__ __launch_bounds__(256, 4) void gemm_qkv(
    const __hip_bfloat16* __restrict__ Xb, const __hip_bfloat16* __restrict__ Wt,
    const float* __restrict__ bias, const int* __restrict__ idx,
    const int* __restrict__ cnt, const int* __restrict__ cnt_pad,
    __hip_bfloat16* __restrict__ Q, __hip_bfloat16* __restrict__ Kc,
    __hip_bfloat16* __restrict__ Vt) {
  const int z = blockIdx.z;
  const int f = blockIdx.x;
  const int xcd = f & 7, loc = f >> 3;
  const int m0 = ((loc & 7) * 2 + (xcd >> 2)) * 128;
  const int n_idx = (loc >> 3) * 4 + (xcd & 3);
  const bool isQ = (n_idx < 8);
  if (!isQ && m0 >= cnt_pad[z]) return;
  const int n0 = (isQ ? n_idx : n_idx - 8) * 128;
  const __hip_bfloat16* A = Xb + (int64_t)z * 2048 * 1024;
  const __hip_bfloat16* Bt = Wt + (isQ ? 0 : (int64_t)1024 * 1024);
  const float* bv = bias + (isQ ? 0 : 1024);

  const int tid = threadIdx.x;
  const int wave = tid >> 6, lane = tid & 63;
  const int quad = lane >> 4, tr = lane & 15, t7 = tr & 7;
  const int wm = wave & 1, wn = wave >> 1;

  // single buffer: lsA 8192 el + lsB 8192 el = 32KB; V-epilogue vt[128][136].
  __shared__ __hip_bfloat16 ls[17408];

  // 32 chunks of 1KB (8 rows x 128B each): 0..15 = A, 16..31 = B. 8/wave.
  const __hip_bfloat16* gsrc[8];
  int loff[8];
  {
    const int srow = lane >> 3;                 // 0..7
    const int kcs = (((lane & 7) ^ srow) * 8);  // swizzled k-chunk (elements)
    const int cz = isQ ? 0 : cnt[z];
    const int* idxz = idx + z * 2048;
#pragma unroll
    for (int cc = 0; cc < 8; ++cc) {
      int c = wave * 8 + cc;
      int isA = (c < 16);
      int cr = isA ? c : (c - 16);
      int row = cr * 8 + srow;
      if (isA) {
        int ar = m0 + row;
        if (!isQ) ar = (ar < cz) ? idxz[ar] : 0;
        gsrc[cc] = A + (int64_t)ar * 1024 + kcs;
      } else {
        gsrc[cc] = Bt + (int64_t)(n0 + row) * 1024 + kcs;
      }
      loff[cc] = (isA ? 0 : 8192) + cr * 512;
    }
  }

  // LDS byte addrs for asm fragment reads (k-half w).
  uint32_t aAd[2], bBd[2];
  {
    uint32_t base = laddr(ls);
#pragma unroll
    for (int w = 0; w < 2; ++w) {
      uint32_t col = (uint32_t)(((((w << 2) | quad)) ^ t7) * 16);
      aAd[w] = base + (wm * 64 + tr) * 128 + col;
      bBd[w] = base + 16384 + (wn * 64 + tr) * 128 + col;
    }
  }

  f32x4 acc[4][4];
#pragma unroll
  for (int mi = 0; mi < 4; ++mi)
#pragma unroll
    for (int ni = 0; ni < 4; ++ni) acc[mi][ni] = (f32x4){0.f, 0.f, 0.f, 0.f};

  bf16x8 af[4], bf[4];

#define STAGE(k0)                                     \
  do {                                                \
    _Pragma("unroll") for (int cc = 0; cc < 8; ++cc)  \
        async_cp16(gsrc[cc] + (k0), ls + loff[cc]);   \
  } while (0)
#define COMP()                                                                \
  do {                                                                        \
    _Pragma("unroll") for (int w = 0; w < 2; ++w) {                           \
      DSR(af[0], aAd[w], 0);                                                  \
      DSR(af[1], aAd[w], 2048);                                               \
      DSR(af[2], aAd[w], 4096);                                               \
      DSR(af[3], aAd[w], 6144);                                               \
      DSR(bf[0], bBd[w], 0);                                                  \
      DSR(bf[1], bBd[w], 2048);                                               \
      DSR(bf[2], bBd[w], 4096);                                               \
      DSR(bf[3], bBd[w], 6144);                                               \
      LGKM0();                                                                \
      _Pragma("unroll") for (int mi = 0; mi < 4; ++mi)                        \
          _Pragma("unroll") for (int ni = 0; ni < 4; ++ni) acc[mi][ni] =      \
              __builtin_amdgcn_mfma_f32_16x16x32_bf16(af[mi], bf[ni],         \
                                                      acc[mi][ni], 0, 0, 0);  \
    }                                                                         \
  } while (0)

  for (int t = 0; t < 16; ++t) {
    BAR();             // prior COMP's reads complete (LGKM0) -> safe restage
    STAGE(t * 64);
    VMW(0);
    BAR();
    COMP();
  }
#undef STAGE
#undef COMP

  // Epilogue. D element (row,col) in 16x16 tile = (quad*4 + r, tr)  [m89]
  const int rowbase = m0 + wm * 64;
  const int colbase = n0 + wn * 64;
  if (isQ) {
    __hip_bfloat16* C = Q + (int64_t)z * 2048 * 1024;
#pragma unroll
    for (int ni = 0; ni < 4; ++ni) {
      int col = colbase + ni * 16 + tr;
      float bb = bv[col];
#pragma unroll
      for (int mi = 0; mi < 4; ++mi) {
        int row = rowbase + mi * 16 + quad * 4;
#pragma unroll
        for (int r = 0; r < 4; ++r)
          C[(int64_t)(row + r) * 1024 + col] =
              __float2bfloat16(acc[mi][ni][r] + bb);
      }
    }
  } else if (n0 < 1024) {  // K half
    __hip_bfloat16* C = Kc + (int64_t)z * 2048 * 1024;
#pragma unroll
    for (int ni = 0; ni < 4; ++ni) {
      int col = colbase + ni * 16 + tr;
      float bb = bv[col];
#pragma unroll
      for (int mi = 0; mi < 4; ++mi) {
        int row = rowbase + mi * 16 + quad * 4;
#pragma unroll
        for (int r = 0; r < 4; ++r)
          C[(int64_t)(row + r) * 1024 + col] =
              __float2bfloat16(acc[mi][ni][r] + bb);
      }
    }
  } else {  // V half -> LDS transpose -> coalesced Vt rows
    __syncthreads();
#pragma unroll
    for (int ni = 0; ni < 4; ++ni) {
      int cl = wn * 64 + ni * 16 + tr;  // block-local d
      float bb = bv[colbase + ni * 16 + tr];
#pragma unroll
      for (int mi = 0; mi < 4; ++mi) {
        int rl = wm * 64 + mi * 16 + quad * 4;  // block-local key
        __hip_bfloat16 h[4];
#pragma unroll
        for (int r = 0; r < 4; ++r) h[r] = __float2bfloat16(acc[mi][ni][r] + bb);
        *(ushort4*)(ls + cl * 136 + rl) = *(const ushort4*)h;
      }
    }
    __syncthreads();
    __hip_bfloat16* Vz = Vt + (int64_t)z * 1024 * 2048;
    const int d0 = n0 - 1024;
    const int seg = tid & 15;
#pragma unroll
    for (int p = 0; p < 8; ++p) {
      int d = p * 16 + (tid >> 4);
      bf16x8 v = *(const bf16x8*)(ls + d * 136 + seg * 8);
      *(bf16x8*)(Vz + (int64_t)(d0 + d) * 2048 + m0 + seg * 8) = v;
    }
  }
}

// ------------------------ scores GEMM + fused exp --------------------------
// e = exp2(scale2 * (Q@Kc^T)) bf16; cols >= cnt -> 0. Row sums -> atomicAdd.
// 128x128 tile, BK=64, single-buffer m97 loop, asm ds_read COMP. LDS 32KB.
__global__ __launch_bounds__(256, 4) void gemm_scores(
    const __hip_bfloat16* __restrict__ Qb, const __hip_bfloat16* __restrict__ Kc,
    __hip_bfloat16* __restrict__ Sc, float* __restrict__ rowsum,
    const int* __restrict__ cnt, const int* __restrict__ cnt_pad,
    float scale2) {
  const int z = blockIdx.z;
  const int f = blockIdx.x;
  const int xcd = f & 7, loc = f >> 3;
  const int m0 = ((loc & 7) * 2 + (xcd >> 2)) * 128;
  const int n0 = ((loc >> 3) * 4 + (xcd & 3)) * 128;
  if (n0 >= cnt_pad[z]) return;
  const __hip_bfloat16* A = Qb + (int64_t)z * 2048 * 1024;
  const __hip_bfloat16* Bt = Kc + (int64_t)z * 2048 * 1024;

  const int tid = threadIdx.x;
  const int wave = tid >> 6, lane = tid & 63;
  const int quad = lane >> 4, tr = lane & 15, t7 = tr & 7;
  const int wm = wave & 1, wn = wave >> 1;

  __shared__ __hip_bfloat16 ls[16384];

  const __hip_bfloat16* gsrc[8];
  int loff[8];
  {
    const int srow = lane >> 3;
    const int kcs = (((lane & 7) ^ srow) * 8);
#pragma unroll
    for (int cc = 0; cc < 8; ++cc) {
      int c = wave * 8 + cc;
      int isA = (c < 16);
      int cr = isA ? c : (c - 16);
      int row = cr * 8 + srow;
      gsrc[cc] = isA ? (A + (int64_t)(m0 + row) * 1024 + kcs)
                     : (Bt + (int64_t)(n0 + row) * 1024 + kcs);
      loff[cc] = (isA ? 0 : 8192) + cr * 512;
    }
  }

  uint32_t aAd[2], bBd[2];
  {
    uint32_t base = laddr(ls);
#pragma unroll
    for (int w = 0; w < 2; ++w) {
      uint32_t col = (uint32_t)(((((w << 2) | quad)) ^ t7) * 16);
      aAd[w] = base + (wm * 64 + tr) * 128 + col;
      bBd[w] = base + 16384 + (wn * 64 + tr) * 128 + col;
    }
  }

  f32x4 acc[4][4];
#pragma unroll
  for (int mi = 0; mi < 4; ++mi)
#pragma unroll
    for (int ni = 0; ni < 4; ++ni) acc[mi][ni] = (f32x4){0.f, 0.f, 0.f, 0.f};

  bf16x8 af[4], bf[4];

#define STAGE(k0)                                     \
  do {                                                \
    _Pragma("unroll") for (int cc = 0; cc < 8; ++cc)  \
        async_cp16(gsrc[cc] + (k0), ls + loff[cc]);   \
  } while (0)
#define COMP()                                                                \
  do {                                                                        \
    _Pragma("unroll") for (int w = 0; w < 2; ++w) {                           \
      DSR(af[0], aAd[w], 0);                                                  \
      DSR(af[1], aAd[w], 2048);                                               \
      DSR(af[2], aAd[w], 4096);                                               \
      DSR(af[3], aAd[w], 6144);                                               \
      DSR(bf[0], bBd[w], 0);                                                  \
      DSR(bf[1], bBd[w], 2048);                                               \
      DSR(bf[2], bBd[w], 4096);                                               \
      DSR(bf[3], bBd[w], 6144);                                               \
      LGKM0();                                                                \
      _Pragma("unroll") for (int mi = 0; mi < 4; ++mi)                        \
          _Pragma("unroll") for (int ni = 0; ni < 4; ++ni) acc[mi][ni] =      \
              __builtin_amdgcn_mfma_f32_16x16x32_bf16(af[mi], bf[ni],         \
                                                      acc[mi][ni], 0, 0, 0);  \
    }                                                                         \
  } while (0)

  for (int t = 0; t < 16; ++t) {
    BAR();
    STAGE(t * 64);
    VMW(0);
    BAR();
    COMP();
  }
#undef STAGE
#undef COMP

  const int rowbase = m0 + wm * 64;
  const int colbase = n0 + wn * 64;
  const int cn = cnt[z];
  __hip_bfloat16* C = Sc + (int64_t)z * 2048 * 2048;

  float psum[4][4];
#pragma unroll
  for (int mi = 0; mi < 4; ++mi)
#pragma unroll
    for (int r = 0; r < 4; ++r) psum[mi][r] = 0.f;

#pragma unroll
  for (int ni = 0; ni < 4; ++ni) {
    int col = colbase + ni * 16 + tr;
    bool valid = (col < cn);
#pragma unroll
    for (int mi = 0; mi < 4; ++mi) {
      int row = rowbase + mi * 16 + quad * 4;
#pragma unroll
      for (int r = 0; r < 4; ++r) {
        float e = valid ? exp2f(acc[mi][ni][r] * scale2) : 0.f;
        C[(int64_t)(row + r) * 2048 + col] = __float2bfloat16(e);
        psum[mi][r] += e;
      }
    }
  }
#pragma unroll
  for (int off = 1; off <= 8; off <<= 1)
#pragma unroll
    for (int mi = 0; mi < 4; ++mi)
#pragma unroll
      for (int r = 0; r < 4; ++r)
        psum[mi][r] += __shfl_xor(psum[mi][r], off, 64);
  if (tr == 0) {
    float* rs = rowsum + z * 2048 + rowbase;
#pragma unroll
    for (int mi = 0; mi < 4; ++mi)
#pragma unroll
      for (int r = 0; r < 4; ++r)
        atomicAdd(&rs[mi * 16 + quad * 4 + r], psum[mi][r]);
  }
}

// --------------------------- PV GEMM + normalize ---------------------------
// out = (E @ Vt^T) / rowsum[row]  (fp32). K = cnt_pad[z]. 128x128 tile,
// BK=64, single-buffer m97 loop, asm ds_read COMP. grid (128,1,4). LDS 32KB.
__global__ __launch_bounds__(256, 4) void gemm_pv(
    const __hip_bfloat16* __restrict__ Sc, const __hip_bfloat16* __restrict__ Vt,
    float* __restrict__ out, const float* __restrict__ rowsum,
    const int* __restrict__ cnt_pad) {
  const int z = blockIdx.z;
  const int f = blockIdx.x;
  const int xcd = f & 7, loc = f >> 3;
  const int m0 = ((loc & 7) * 2 + (xcd >> 2)) * 128;
  const int n0 = ((loc >> 3) * 4 + (xcd & 3)) * 128;
  const int Ks = cnt_pad[z];
  const __hip_bfloat16* A = Sc + (int64_t)z * 2048 * 2048;
  const __hip_bfloat16* Bt = Vt + (int64_t)z * 1024 * 2048;

  const int tid = threadIdx.x;
  const int wave = tid >> 6, lane = tid & 63;
  const int quad = lane >> 4, tr = lane & 15, t7 = tr & 7;
  const int wm = wave & 1, wn = wave >> 1;

  __shared__ __hip_bfloat16 ls[16384];

  const __hip_bfloat16* gsrc[8];
  int loff[8];
  {
    const int srow = lane >> 3;
    const int kcs = (((lane & 7) ^ srow) * 8);
#pragma unroll
    for (int cc = 0; cc < 8; ++cc) {
      int c = wave * 8 + cc;
      int isA = (c < 16);
      int cr = isA ? c : (c - 16);
      int row = cr * 8 + srow;
      gsrc[cc] = isA ? (A + (int64_t)(m0 + row) * 2048 + kcs)
                     : (Bt + (int64_t)(n0 + row) * 2048 + kcs);
      loff[cc] = (isA ? 0 : 8192) + cr * 512;
    }
  }

  uint32_t aAd[2], bBd[2];
  {
    uint32_t base = laddr(ls);
#pragma unroll
    for (int w = 0; w < 2; ++w) {
      uint32_t col = (uint32_t)(((((w << 2) | quad)) ^ t7) * 16);
      aAd[w] = base + (wm * 64 + tr) * 128 + col;
      bBd[w] = base + 16384 + (wn * 64 + tr) * 128 + col;
    }
  }

  f32x4 acc[4][4];
#pragma unroll
  for (int mi = 0; mi < 4; ++mi)
#pragma unroll
    for (int ni = 0; ni < 4; ++ni) acc[mi][ni] = (f32x4){0.f, 0.f, 0.f, 0.f};

  bf16x8 af[4], bf[4];

#define STAGE(k0)                                     \
  do {                                                \
    _Pragma("unroll") for (int cc = 0; cc < 8; ++cc)  \
        async_cp16(gsrc[cc] + (k0), ls + loff[cc]);   \
  } while (0)
#define COMP()                                                                \
  do {                                                                        \
    _Pragma("unroll") for (int w = 0; w < 2; ++w) {                           \
      DSR(af[0], aAd[w], 0);                                                  \
      DSR(af[1], aAd[w], 2048);                                               \
      DSR(af[2], aAd[w], 4096);                                               \
      DSR(af[3], aAd[w], 6144);                                               \
      DSR(bf[0], bBd[w], 0);                                                  \
      DSR(bf[1], bBd[w], 2048);                                               \
      DSR(bf[2], bBd[w], 4096);                                               \
      DSR(bf[3], bBd[w], 6144);                                               \
      LGKM0();                                                                \
      _Pragma("unroll") for (int mi = 0; mi < 4; ++mi)                        \
          _Pragma("unroll") for (int ni = 0; ni < 4; ++ni) acc[mi][ni] =      \
              __builtin_amdgcn_mfma_f32_16x16x32_bf16(af[mi], bf[ni],         \
                                                      acc[mi][ni], 0, 0, 0);  \
    }                                                                         \
  } while (0)

  const int NT = Ks >> 6;  // K-tiles
  for (int t = 0; t < NT; ++t) {
    BAR();
    STAGE(t * 64);
    VMW(0);
    BAR();
    COMP();
  }
#undef STAGE
#undef COMP

  const int rowbase = m0 + wm * 64;
  const int colbase = n0 + wn * 64;
  const float* rs = rowsum + z * 2048 + rowbase;
  float invv[4][4];
#pragma unroll
  for (int mi = 0; mi < 4; ++mi)
#pragma unroll
    for (int r = 0; r < 4; ++r) invv[mi][r] = 1.0f / rs[mi * 16 + quad * 4 + r];

  float* C = out + (int64_t)z * 2048 * 1024;
#pragma unroll
  for (int ni = 0; ni < 4; ++ni) {
    int col = colbase + ni * 16 + tr;
#pragma unroll
    for (int mi = 0; mi < 4; ++mi) {
      int row = rowbase + mi * 16 + quad * 4;
#pragma unroll
      for (int r = 0; r < 4; ++r)
        C[(int64_t)(row + r) * 1024 + col] = acc[mi][ni][r] * invv[mi][r];
    }
  }
}

// ------------------------------- launcher ----------------------------------
extern "C" void kernel_launch(void* const* d_in, const int* in_sizes, int n_in,
                              void* d_out, int out_size, void* d_ws,
                              size_t ws_size, hipStream_t stream) {
  const float* X = (const float*)d_in[0];        // (4,2048,1024) fp32
  const int* mask = (const int*)d_in[1];         // (4,2048) bool->int32
  const float* W = (const float*)d_in[2];        // (1024,3072) fp32
  const float* bias = (const float*)d_in[3];     // (3072,) fp32
  float* out = (float*)d_out;                    // (4,2048,1024) fp32

  char* ws = (char*)d_ws;
  auto alloc = [&](size_t bytes) {
    char* p = ws;
    ws += (bytes + 255) & ~(size_t)255;
    return p;
  };
  __hip_bfloat16* Xb = (__hip_bfloat16*)alloc(8192ULL * 1024 * 2);      // 16.8 MB
  __hip_bfloat16* Wt = (__hip_bfloat16*)alloc(3072ULL * 1024 * 2);      //  6.3 MB
  __hip_bfloat16* Q = (__hip_bfloat16*)alloc(8192ULL * 1024 * 2);       // 16.8 MB
  __hip_bfloat16* Kc = (__hip_bfloat16*)alloc(4ULL * 2048 * 1024 * 2);  // 16.8 MB
  __hip_bfloat16* Vt = (__hip_bfloat16*)alloc(4ULL * 1024 * 2048 * 2);  // 16.8 MB
  __hip_bfloat16* Sc = (__hip_bfloat16*)alloc(4ULL * 2048 * 2048 * 2);  // 33.6 MB
  float* rowsum = (float*)alloc(8192ULL * 4);                           // 32 KB
  int* idx = (int*)alloc(4ULL * 2048 * 4);
  int* cnt = (int*)alloc(64);
  int* cnt_pad = (int*)alloc(64);

  // 0) rowsum = 0 (ws is poisoned 0xAA before every launch)
  hipMemsetAsync(rowsum, 0, 8192ULL * 4, stream);
  // 1) X -> bf16
  cvt_f32_bf16<<<8192, 256, 0, stream>>>(X, Xb, 8192 * 1024);
  // 2) W -> W^T bf16  (Bt layout [N][K])
  transpose_cvt_f32<<<dim3(96, 32, 1), dim3(32, 8), 0, stream>>>(W, 3072, Wt,
                                                                 1024);
  // 3) mask -> compacted index list (cnt_pad 128-aligned)
  mask_scan<<<4, 256, 0, stream>>>(mask, idx, cnt, cnt_pad);
  // 4) merged Q + K + V^T (swizzled; V transposed via LDS in epilogue)
  gemm_qkv<<<dim3(384, 1, 4), 256, 0, stream>>>(Xb, Wt, bias, idx, cnt,
                                                cnt_pad, Q, Kc, Vt);
  // 5) E = exp2(log2e/32 * Q@Kc^T) -> bf16, rowsum += per-row sums
  gemm_scores<<<dim3(256, 1, 4), 256, 0, stream>>>(
      Q, Kc, Sc, rowsum, cnt, cnt_pad, 0.03125f * 1.4426950408889634f);
  // 6) out = (E @ Vt^T) / rowsum  (fp32, K = cnt_pad)
  gemm_pv<<<dim3(128, 1, 4), 256, 0, stream>>>(Sc, Vt, out, rowsum, cnt_pad);
}

// Round 8
// 191.654 us; speedup vs baseline: 1.1178x; 1.0878x over previous
//
#include <hip/hip_runtime.h>
#include <hip/hip_bf16.h>
#include <stdint.h>

// ---------------------------------------------------------------------------
// SelfAttention: QKV = X@W + b ; S = QK^T/32 (mask -> -inf) ; O = softmax(S)@V
// B=4, S=2048, H=1024.  bf16 MFMA path.
// R16: R13 GEMMs verbatim (best: 204.7us; qkv 51.2, MfmaUtil 26%) + merged
//     prep kernel. Across R8-R15, total-qkv is CONSTANT (153-160us) while
//     scores/pv structures changed radically -> suspect fixed per-node graph
//     overhead. cvt + W-transpose + mask-scan + rowsum-zero now ONE kernel
//     (blockIdx-partitioned); memset node dropped. Graph: 7 -> 4 nodes.
//     Falsifier: total >=200 -> overhead theory dead, scores/pv are the gap.
// ---------------------------------------------------------------------------

typedef __attribute__((ext_vector_type(8))) short bf16x8;   // 8 bf16 = 4 VGPRs
typedef __attribute__((ext_vector_type(4))) float f32x4;

__device__ __forceinline__ void async_cp16(const void* g, void* l) {
  __builtin_amdgcn_global_load_lds(
      (const __attribute__((address_space(1))) void*)g,
      (__attribute__((address_space(3))) void*)l, 16, 0, 0);
}

__device__ __forceinline__ uint32_t laddr(const void* p) {
  return (uint32_t)(uintptr_t)(const __attribute__((address_space(3))) void*)p;
}

#define FENCE() asm volatile("" ::: "memory")
#define BAR()                           \
  do {                                  \
    FENCE();                            \
    __builtin_amdgcn_s_barrier();       \
    FENCE();                            \
  } while (0)
#define VMW(N) asm volatile("s_waitcnt vmcnt(" #N ")" ::: "memory")
#define LGKM0()                                            \
  do {                                                     \
    asm volatile("s_waitcnt lgkmcnt(0)" ::: "memory");     \
    __builtin_amdgcn_sched_barrier(0);                     \
  } while (0)
// asm ds_read_b128 with literal byte offset; no memory operand on purpose.
#define DSR(dst, a, OFF) \
  asm volatile("ds_read_b128 %0, %1 offset:" #OFF : "=v"(dst) : "v"(a))

// ------------------- merged prep: cvt + W^T + mask + zero -------------------
// grid: [0,8192)        cvt X -> bf16 (1024 el/block)
//       [8192,11264)    W 32x32 transpose-cvt tile (t = b-8192: bx=t%96,by=t/96)
//       [11264,11268)   mask scan for z = b-11264, + zero rowsum[z]
__global__ __launch_bounds__(256) void prep(
    const float* __restrict__ X, __hip_bfloat16* __restrict__ Xb,
    const float* __restrict__ W, __hip_bfloat16* __restrict__ Wt,
    const int* __restrict__ mask, int* __restrict__ idx,
    int* __restrict__ cnt, int* __restrict__ cnt_pad,
    float* __restrict__ rowsum) {
  const int b = blockIdx.x;
  const int tid = threadIdx.x;
  if (b < 8192) {
    int i = (b * 256 + tid) * 4;
    float4 f = *(const float4*)(X + i);
    __hip_bfloat16 o[4];
    o[0] = __float2bfloat16(f.x);
    o[1] = __float2bfloat16(f.y);
    o[2] = __float2bfloat16(f.z);
    o[3] = __float2bfloat16(f.w);
    *(ushort4*)(Xb + i) = *(const ushort4*)o;
    return;
  }
  if (b < 11264) {
    __shared__ float tile[32][33];
    const int t = b - 8192;
    const int bx = (t % 96) * 32;   // src col (of 3072)
    const int by = (t / 96) * 32;   // src row (of 1024)
    const int tx = tid & 31, ty = tid >> 5;
#pragma unroll
    for (int j = 0; j < 4; ++j)
      tile[ty + j * 8][tx] = W[(int64_t)(by + ty + j * 8) * 3072 + bx + tx];
    __syncthreads();
#pragma unroll
    for (int j = 0; j < 4; ++j)
      Wt[(int64_t)(bx + ty + j * 8) * 1024 + by + tx] =
          __float2bfloat16(tile[tx][ty + j * 8]);
    return;
  }
  {
    const int z = b - 11264;
    const int* mz = mask + z * 2048;
    int* iz = idx + z * 2048;
    const int lane = tid & 63, wave = tid >> 6;
    // zero rowsum for this z
    float* rs = rowsum + z * 2048;
#pragma unroll
    for (int j = 0; j < 8; ++j) rs[tid + j * 256] = 0.f;

    int keep[8];
    int local = 0;
#pragma unroll
    for (int j = 0; j < 8; ++j) {
      keep[j] = (mz[tid * 8 + j] == 0);
      local += keep[j];
    }
    int pre = local;  // inclusive wave scan
#pragma unroll
    for (int off = 1; off <= 32; off <<= 1) {
      int n = __shfl_up(pre, off, 64);
      if (lane >= off) pre += n;
    }
    __shared__ int wsum[4];
    if (lane == 63) wsum[wave] = pre;
    __syncthreads();
    int base = 0;
    for (int w = 0; w < wave; ++w) base += wsum[w];
    int excl = base + pre - local;
#pragma unroll
    for (int j = 0; j < 8; ++j)
      if (keep[j]) iz[excl++] = tid * 8 + j;
    if (tid == 255) {
      int tot = base + pre;
      cnt[z] = tot;
      cnt_pad[z] = (tot + 127) & ~127;
    }
  }
}

// --------------------------- merged Q+K+V GEMM -----------------------------
// grid (384, 1, B).  Swizzled flat id: xcd=f&7, loc=f>>3 in [0,48):
//   m_idx = (loc&7)*2 + (xcd>>2); n_idx = (loc>>3)*4 + (xcd&3) in [0,24)
// n_idx<8:  Q  = Xb[z] @ Wt[0:1024]^T + b      (all 2048 rows)
// n_idx>=8: KV = gather(Xb[z], idx) @ Wt[1024:3072]^T + b, rows < cnt_pad[z]
// 128x128 tile, 256 thr, BK=64, dbuf prefetch, asm ds_read fragments.
__global__ __launch_bounds__(256) void gemm_qkv(
    const __hip_bfloat16* __restrict__ Xb, const __hip_bfloat16* __restrict__ Wt,
    const float* __restrict__ bias, const int* __restrict__ idx,
    const int* __restrict__ cnt, const int* __restrict__ cnt_pad,
    __hip_bfloat16* __restrict__ Q, __hip_bfloat16* __restrict__ Kc,
    __hip_bfloat16* __restrict__ Vt) {
  const int z = blockIdx.z;
  const int f = blockIdx.x;
  const int xcd = f & 7, loc = f >> 3;
  const int m0 = ((loc & 7) * 2 + (xcd >> 2)) * 128;
  const int n_idx = (loc >> 3) * 4 + (xcd & 3);
  const bool isQ = (n_idx < 8);
  if (!isQ && m0 >= cnt_pad[z]) return;
  const int n0 = (isQ ? n_idx : n_idx - 8) * 128;
  const __hip_bfloat16* A = Xb + (int64_t)z * 2048 * 1024;
  const __hip_bfloat16* Bt = Wt + (isQ ? 0 : (int64_t)1024 * 1024);
  const float* bv = bias + (isQ ? 0 : 1024);

  const int tid = threadIdx.x;
  const int wave = tid >> 6, lane = tid & 63;
  const int quad = lane >> 4, tr = lane & 15, t7 = tr & 7;
  const int wm = wave & 1, wn = wave >> 1;

  // 2 bufs x (lsA 8192 el + lsB 8192 el) = 64KB; V-epilogue reuses as
  // vt[128][136].
  __shared__ __hip_bfloat16 ls[32768];

  // 32 chunks of 1KB (8 rows x 128B each): 0..15 = A, 16..31 = B. 8/wave.
  const __hip_bfloat16* gsrc[8];
  int loff[8];  // element offset within one buffer
  {
    const int srow = lane >> 3;                 // 0..7
    const int kcs = (((lane & 7) ^ srow) * 8);  // swizzled k-chunk (elements)
    const int cz = isQ ? 0 : cnt[z];
    const int* idxz = idx + z * 2048;
#pragma unroll
    for (int cc = 0; cc < 8; ++cc) {
      int c = wave * 8 + cc;
      int isA = (c < 16);
      int cr = isA ? c : (c - 16);
      int row = cr * 8 + srow;
      if (isA) {
        int ar = m0 + row;
        if (!isQ) ar = (ar < cz) ? idxz[ar] : 0;
        gsrc[cc] = A + (int64_t)ar * 1024 + kcs;
      } else {
        gsrc[cc] = Bt + (int64_t)(n0 + row) * 1024 + kcs;
      }
      loff[cc] = (isA ? 0 : 8192) + cr * 512;
    }
  }

  // LDS byte addrs for asm fragment reads (buf, k-half w).
  uint32_t aAd[2][2], bBd[2][2];
  {
    uint32_t base = laddr(ls);
#pragma unroll
    for (int b = 0; b < 2; ++b)
#pragma unroll
      for (int w = 0; w < 2; ++w) {
        uint32_t col = (uint32_t)(((((w << 2) | quad)) ^ t7) * 16);
        aAd[b][w] = base + b * 32768 + (wm * 64 + tr) * 128 + col;
        bBd[b][w] = base + b * 32768 + 16384 + (wn * 64 + tr) * 128 + col;
      }
  }

  f32x4 acc[4][4];
#pragma unroll
  for (int mi = 0; mi < 4; ++mi)
#pragma unroll
    for (int ni = 0; ni < 4; ++ni) acc[mi][ni] = (f32x4){0.f, 0.f, 0.f, 0.f};

  bf16x8 af[4], bf[4];

#define STAGE(BUF, k0)                                            \
  do {                                                            \
    _Pragma("unroll") for (int cc = 0; cc < 8; ++cc)              \
        async_cp16(gsrc[cc] + (k0), ls + (BUF)*16384 + loff[cc]); \
  } while (0)
#define COMP(BUF)                                                             \
  do {                                                                        \
    _Pragma("unroll") for (int w = 0; w < 2; ++w) {                           \
      DSR(af[0], aAd[BUF][w], 0);                                             \
      DSR(af[1], aAd[BUF][w], 2048);                                          \
      DSR(af[2], aAd[BUF][w], 4096);                                          \
      DSR(af[3], aAd[BUF][w], 6144);                                          \
      DSR(bf[0], bBd[BUF][w], 0);                                             \
      DSR(bf[1], bBd[BUF][w], 2048);                                          \
      DSR(bf[2], bBd[BUF][w], 4096);                                          \
      DSR(bf[3], bBd[BUF][w], 6144);                                          \
      LGKM0();                                                                \
      _Pragma("unroll") for (int mi = 0; mi < 4; ++mi)                        \
          _Pragma("unroll") for (int ni = 0; ni < 4; ++ni) acc[mi][ni] =      \
              __builtin_amdgcn_mfma_f32_16x16x32_bf16(af[mi], bf[ni],         \
                                                      acc[mi][ni], 0, 0, 0);  \
    }                                                                         \
  } while (0)

  STAGE(0, 0);
  for (int it = 0; it < 8; ++it) {
    STAGE(1, (2 * it + 1) * 64);
    VMW(8); BAR();
    COMP(0);
    BAR();
    if (it < 7) {
      STAGE(0, (2 * it + 2) * 64);
      VMW(8);
    } else {
      VMW(0);
    }
    BAR();
    COMP(1);
    BAR();
  }
#undef STAGE
#undef COMP

  // Epilogue. D element (row,col) in 16x16 tile = (quad*4 + r, tr)  [m89]
  const int rowbase = m0 + wm * 64;
  const int colbase = n0 + wn * 64;
  if (isQ) {
    __hip_bfloat16* C = Q + (int64_t)z * 2048 * 1024;
#pragma unroll
    for (int ni = 0; ni < 4; ++ni) {
      int col = colbase + ni * 16 + tr;
      float bb = bv[col];
#pragma unroll
      for (int mi = 0; mi < 4; ++mi) {
        int row = rowbase + mi * 16 + quad * 4;
#pragma unroll
        for (int r = 0; r < 4; ++r)
          C[(int64_t)(row + r) * 1024 + col] =
              __float2bfloat16(acc[mi][ni][r] + bb);
      }
    }
  } else if (n0 < 1024) {  // K half
    __hip_bfloat16* C = Kc + (int64_t)z * 2048 * 1024;
#pragma unroll
    for (int ni = 0; ni < 4; ++ni) {
      int col = colbase + ni * 16 + tr;
      float bb = bv[col];
#pragma unroll
      for (int mi = 0; mi < 4; ++mi) {
        int row = rowbase + mi * 16 + quad * 4;
#pragma unroll
        for (int r = 0; r < 4; ++r)
          C[(int64_t)(row + r) * 1024 + col] =
              __float2bfloat16(acc[mi][ni][r] + bb);
      }
    }
  } else {  // V half -> LDS transpose -> coalesced Vt rows
    __syncthreads();
#pragma unroll
    for (int ni = 0; ni < 4; ++ni) {
      int cl = wn * 64 + ni * 16 + tr;  // block-local d
      float bb = bv[colbase + ni * 16 + tr];
#pragma unroll
      for (int mi = 0; mi < 4; ++mi) {
        int rl = wm * 64 + mi * 16 + quad * 4;  // block-local key
        __hip_bfloat16 h[4];
#pragma unroll
        for (int r = 0; r < 4; ++r) h[r] = __float2bfloat16(acc[mi][ni][r] + bb);
        *(ushort4*)(ls + cl * 136 + rl) = *(const ushort4*)h;
      }
    }
    __syncthreads();
    __hip_bfloat16* Vz = Vt + (int64_t)z * 1024 * 2048;
    const int d0 = n0 - 1024;
    const int seg = tid & 15;
#pragma unroll
    for (int p = 0; p < 8; ++p) {
      int d = p * 16 + (tid >> 4);
      bf16x8 v = *(const bf16x8*)(ls + d * 136 + seg * 8);
      *(bf16x8*)(Vz + (int64_t)(d0 + d) * 2048 + m0 + seg * 8) = v;
    }
  }
}

// ------------------------ scores GEMM + fused exp --------------------------
// e = exp2(scale2 * (Q@Kc^T)) bf16; cols >= cnt -> 0. Row sums -> atomicAdd.
// 128x128 tile, BK=64, dbuf prefetch, asm ds_read fragments. grid (256,1,4).
__global__ __launch_bounds__(256) void gemm_scores(
    const __hip_bfloat16* __restrict__ Qb, const __hip_bfloat16* __restrict__ Kc,
    __hip_bfloat16* __restrict__ Sc, float* __restrict__ rowsum,
    const int* __restrict__ cnt, const int* __restrict__ cnt_pad,
    float scale2) {
  const int z = blockIdx.z;
  const int f = blockIdx.x;
  const int xcd = f & 7, loc = f >> 3;
  const int m0 = ((loc & 7) * 2 + (xcd >> 2)) * 128;
  const int n0 = ((loc >> 3) * 4 + (xcd & 3)) * 128;
  if (n0 >= cnt_pad[z]) return;
  const __hip_bfloat16* A = Qb + (int64_t)z * 2048 * 1024;
  const __hip_bfloat16* Bt = Kc + (int64_t)z * 2048 * 1024;

  const int tid = threadIdx.x;
  const int wave = tid >> 6, lane = tid & 63;
  const int quad = lane >> 4, tr = lane & 15, t7 = tr & 7;
  const int wm = wave & 1, wn = wave >> 1;

  __shared__ __hip_bfloat16 ls[32768];

  const __hip_bfloat16* gsrc[8];
  int loff[8];
  {
    const int srow = lane >> 3;
    const int kcs = (((lane & 7) ^ srow) * 8);
#pragma unroll
    for (int cc = 0; cc < 8; ++cc) {
      int c = wave * 8 + cc;
      int isA = (c < 16);
      int cr = isA ? c : (c - 16);
      int row = cr * 8 + srow;
      gsrc[cc] = isA ? (A + (int64_t)(m0 + row) * 1024 + kcs)
                     : (Bt + (int64_t)(n0 + row) * 1024 + kcs);
      loff[cc] = (isA ? 0 : 8192) + cr * 512;
    }
  }

  uint32_t aAd[2][2], bBd[2][2];
  {
    uint32_t base = laddr(ls);
#pragma unroll
    for (int b = 0; b < 2; ++b)
#pragma unroll
      for (int w = 0; w < 2; ++w) {
        uint32_t col = (uint32_t)(((((w << 2) | quad)) ^ t7) * 16);
        aAd[b][w] = base + b * 32768 + (wm * 64 + tr) * 128 + col;
        bBd[b][w] = base + b * 32768 + 16384 + (wn * 64 + tr) * 128 + col;
      }
  }

  f32x4 acc[4][4];
#pragma unroll
  for (int mi = 0; mi < 4; ++mi)
#pragma unroll
    for (int ni = 0; ni < 4; ++ni) acc[mi][ni] = (f32x4){0.f, 0.f, 0.f, 0.f};

  bf16x8 af[4], bf[4];

#define STAGE(BUF, k0)                                            \
  do {                                                            \
    _Pragma("unroll") for (int cc = 0; cc < 8; ++cc)              \
        async_cp16(gsrc[cc] + (k0), ls + (BUF)*16384 + loff[cc]); \
  } while (0)
#define COMP(BUF)                                                             \
  do {                                                                        \
    _Pragma("unroll") for (int w = 0; w < 2; ++w) {                           \
      DSR(af[0], aAd[BUF][w], 0);                                             \
      DSR(af[1], aAd[BUF][w], 2048);                                          \
      DSR(af[2], aAd[BUF][w], 4096);                                          \
      DSR(af[3], aAd[BUF][w], 6144);                                          \
      DSR(bf[0], bBd[BUF][w], 0);                                             \
      DSR(bf[1], bBd[BUF][w], 2048);                                          \
      DSR(bf[2], bBd[BUF][w], 4096);                                          \
      DSR(bf[3], bBd[BUF][w], 6144);                                          \
      LGKM0();                                                                \
      _Pragma("unroll") for (int mi = 0; mi < 4; ++mi)                        \
          _Pragma("unroll") for (int ni = 0; ni < 4; ++ni) acc[mi][ni] =      \
              __builtin_amdgcn_mfma_f32_16x16x32_bf16(af[mi], bf[ni],         \
                                                      acc[mi][ni], 0, 0, 0);  \
    }                                                                         \
  } while (0)

  STAGE(0, 0);
  for (int it = 0; it < 8; ++it) {
    STAGE(1, (2 * it + 1) * 64);
    VMW(8); BAR();
    COMP(0);
    BAR();
    if (it < 7) {
      STAGE(0, (2 * it + 2) * 64);
      VMW(8);
    } else {
      VMW(0);
    }
    BAR();
    COMP(1);
    BAR();
  }
#undef STAGE
#undef COMP

  const int rowbase = m0 + wm * 64;
  const int colbase = n0 + wn * 64;
  const int cn = cnt[z];
  __hip_bfloat16* C = Sc + (int64_t)z * 2048 * 2048;

  float psum[4][4];
#pragma unroll
  for (int mi = 0; mi < 4; ++mi)
#pragma unroll
    for (int r = 0; r < 4; ++r) psum[mi][r] = 0.f;

#pragma unroll
  for (int ni = 0; ni < 4; ++ni) {
    int col = colbase + ni * 16 + tr;
    bool valid = (col < cn);
#pragma unroll
    for (int mi = 0; mi < 4; ++mi) {
      int row = rowbase + mi * 16 + quad * 4;
#pragma unroll
      for (int r = 0; r < 4; ++r) {
        float e = valid ? exp2f(acc[mi][ni][r] * scale2) : 0.f;
        C[(int64_t)(row + r) * 2048 + col] = __float2bfloat16(e);
        psum[mi][r] += e;
      }
    }
  }
#pragma unroll
  for (int off = 1; off <= 8; off <<= 1)
#pragma unroll
    for (int mi = 0; mi < 4; ++mi)
#pragma unroll
      for (int r = 0; r < 4; ++r)
        psum[mi][r] += __shfl_xor(psum[mi][r], off, 64);
  if (tr == 0) {
    float* rs = rowsum + z * 2048 + rowbase;
#pragma unroll
    for (int mi = 0; mi < 4; ++mi)
#pragma unroll
      for (int r = 0; r < 4; ++r)
        atomicAdd(&rs[mi * 16 + quad * 4 + r], psum[mi][r]);
  }
}

// --------------------------- PV GEMM + normalize ---------------------------
// out = (E @ Vt^T) / rowsum[row]  (fp32). K = cnt_pad[z]. 128x128 tile,
// BK=64, dbuf prefetch, asm ds_read fragments. grid (128,1,4).
__global__ __launch_bounds__(256) void gemm_pv(
    const __hip_bfloat16* __restrict__ Sc, const __hip_bfloat16* __restrict__ Vt,
    float* __restrict__ out, const float* __restrict__ rowsum,
    const int* __restrict__ cnt_pad) {
  const int z = blockIdx.z;
  const int f = blockIdx.x;
  const int xcd = f & 7, loc = f >> 3;
  const int m0 = ((loc & 7) * 2 + (xcd >> 2)) * 128;
  const int n0 = ((loc >> 3) * 4 + (xcd & 3)) * 128;
  const int Ks = cnt_pad[z];
  const __hip_bfloat16* A = Sc + (int64_t)z * 2048 * 2048;
  const __hip_bfloat16* Bt = Vt + (int64_t)z * 1024 * 2048;

  const int tid = threadIdx.x;
  const int wave = tid >> 6, lane = tid & 63;
  const int quad = lane >> 4, tr = lane & 15, t7 = tr & 7;
  const int wm = wave & 1, wn = wave >> 1;

  __shared__ __hip_bfloat16 ls[32768];

  const __hip_bfloat16* gsrc[8];
  int loff[8];
  {
    const int srow = lane >> 3;
    const int kcs = (((lane & 7) ^ srow) * 8);
#pragma unroll
    for (int cc = 0; cc < 8; ++cc) {
      int c = wave * 8 + cc;
      int isA = (c < 16);
      int cr = isA ? c : (c - 16);
      int row = cr * 8 + srow;
      gsrc[cc] = isA ? (A + (int64_t)(m0 + row) * 2048 + kcs)
                     : (Bt + (int64_t)(n0 + row) * 2048 + kcs);
      loff[cc] = (isA ? 0 : 8192) + cr * 512;
    }
  }

  uint32_t aAd[2][2], bBd[2][2];
  {
    uint32_t base = laddr(ls);
#pragma unroll
    for (int b = 0; b < 2; ++b)
#pragma unroll
      for (int w = 0; w < 2; ++w) {
        uint32_t col = (uint32_t)(((((w << 2) | quad)) ^ t7) * 16);
        aAd[b][w] = base + b * 32768 + (wm * 64 + tr) * 128 + col;
        bBd[b][w] = base + b * 32768 + 16384 + (wn * 64 + tr) * 128 + col;
      }
  }

  f32x4 acc[4][4];
#pragma unroll
  for (int mi = 0; mi < 4; ++mi)
#pragma unroll
    for (int ni = 0; ni < 4; ++ni) acc[mi][ni] = (f32x4){0.f, 0.f, 0.f, 0.f};

  bf16x8 af[4], bf[4];

#define STAGE(BUF, k0)                                            \
  do {                                                            \
    _Pragma("unroll") for (int cc = 0; cc < 8; ++cc)              \
        async_cp16(gsrc[cc] + (k0), ls + (BUF)*16384 + loff[cc]); \
  } while (0)
#define COMP(BUF)                                                             \
  do {                                                                        \
    _Pragma("unroll") for (int w = 0; w < 2; ++w) {                           \
      DSR(af[0], aAd[BUF][w], 0);                                             \
      DSR(af[1], aAd[BUF][w], 2048);                                          \
      DSR(af[2], aAd[BUF][w], 4096);                                          \
      DSR(af[3], aAd[BUF][w], 6144);                                          \
      DSR(bf[0], bBd[BUF][w], 0);                                             \
      DSR(bf[1], bBd[BUF][w], 2048);                                          \
      DSR(bf[2], bBd[BUF][w], 4096);                                          \
      DSR(bf[3], bBd[BUF][w], 6144);                                          \
      LGKM0();                                                                \
      _Pragma("unroll") for (int mi = 0; mi < 4; ++mi)                        \
          _Pragma("unroll") for (int ni = 0; ni < 4; ++ni) acc[mi][ni] =      \
              __builtin_amdgcn_mfma_f32_16x16x32_bf16(af[mi], bf[ni],         \
                                                      acc[mi][ni], 0, 0, 0);  \
    }                                                                         \
  } while (0)

  const int NP = Ks >> 7;  // K-tile pairs (cnt_pad is 128-aligned)
  STAGE(0, 0);
  for (int it = 0; it < NP; ++it) {
    STAGE(1, (2 * it + 1) * 64);
    VMW(8); BAR();
    COMP(0);
    BAR();
    if (it + 1 < NP) {
      STAGE(0, (2 * it + 2) * 64);
      VMW(8);
    } else {
      VMW(0);
    }
    BAR();
    COMP(1);
    BAR();
  }
#undef STAGE
#undef COMP

  const int rowbase = m0 + wm * 64;
  const int colbase = n0 + wn * 64;
  const float* rs = rowsum + z * 2048 + rowbase;
  float invv[4][4];
#pragma unroll
  for (int mi = 0; mi < 4; ++mi)
#pragma unroll
    for (int r = 0; r < 4; ++r) invv[mi][r] = 1.0f / rs[mi * 16 + quad * 4 + r];

  float* C = out + (int64_t)z * 2048 * 1024;
#pragma unroll
  for (int ni = 0; ni < 4; ++ni) {
    int col = colbase + ni * 16 + tr;
#pragma unroll
    for (int mi = 0; mi < 4; ++mi) {
      int row = rowbase + mi * 16 + quad * 4;
#pragma unroll
      for (int r = 0; r < 4; ++r)
        C[(int64_t)(row + r) * 1024 + col] = acc[mi][ni][r] * invv[mi][r];
    }
  }
}

// ------------------------------- launcher ----------------------------------
extern "C" void kernel_launch(void* const* d_in, const int* in_sizes, int n_in,
                              void* d_out, int out_size, void* d_ws,
                              size_t ws_size, hipStream_t stream) {
  const float* X = (const float*)d_in[0];        // (4,2048,1024) fp32
  const int* mask = (const int*)d_in[1];         // (4,2048) bool->int32
  const float* W = (const float*)d_in[2];        // (1024,3072) fp32
  const float* bias = (const float*)d_in[3];     // (3072,) fp32
  float* out = (float*)d_out;                    // (4,2048,1024) fp32

  char* ws = (char*)d_ws;
  auto alloc = [&](size_t bytes) {
    char* p = ws;
    ws += (bytes + 255) & ~(size_t)255;
    return p;
  };
  __hip_bfloat16* Xb = (__hip_bfloat16*)alloc(8192ULL * 1024 * 2);      // 16.8 MB
  __hip_bfloat16* Wt = (__hip_bfloat16*)alloc(3072ULL * 1024 * 2);      //  6.3 MB
  __hip_bfloat16* Q = (__hip_bfloat16*)alloc(8192ULL * 1024 * 2);       // 16.8 MB
  __hip_bfloat16* Kc = (__hip_bfloat16*)alloc(4ULL * 2048 * 1024 * 2);  // 16.8 MB
  __hip_bfloat16* Vt = (__hip_bfloat16*)alloc(4ULL * 1024 * 2048 * 2);  // 16.8 MB
  __hip_bfloat16* Sc = (__hip_bfloat16*)alloc(4ULL * 2048 * 2048 * 2);  // 33.6 MB
  float* rowsum = (float*)alloc(8192ULL * 4);                           // 32 KB
  int* idx = (int*)alloc(4ULL * 2048 * 4);
  int* cnt = (int*)alloc(64);
  int* cnt_pad = (int*)alloc(64);

  // 1) merged prep: X->bf16, W->W^T bf16, mask->index list, rowsum=0
  prep<<<11268, 256, 0, stream>>>(X, Xb, W, Wt, mask, idx, cnt, cnt_pad,
                                  rowsum);
  // 2) merged Q + K + V^T (swizzled; V transposed via LDS in epilogue)
  gemm_qkv<<<dim3(384, 1, 4), 256, 0, stream>>>(Xb, Wt, bias, idx, cnt,
                                                cnt_pad, Q, Kc, Vt);
  // 3) E = exp2(log2e/32 * Q@Kc^T) -> bf16, rowsum += per-row sums
  gemm_scores<<<dim3(256, 1, 4), 256, 0, stream>>>(
      Q, Kc, Sc, rowsum, cnt, cnt_pad, 0.03125f * 1.4426950408889634f);
  // 4) out = (E @ Vt^T) / rowsum  (fp32, K = cnt_pad)
  gemm_pv<<<dim3(128, 1, 4), 256, 0, stream>>>(Sc, Vt, out, rowsum, cnt_pad);
}